// Round 8
// baseline (341.323 us; speedup 1.0000x reference)
//
#include <hip/hip_runtime.h>

constexpr int NS = 64;          // samples
constexpr int NA = 64;          // agents per sample
constexpr int NN = NS * NA;     // 4096 nodes
constexpr int FD = 128;         // feature dim
constexpr int ZD = 2 * FD + 2;  // 258
constexpr int FS = 16;          // feature-slice width per block
constexpr int NB = NS * (FD / FS); // 512 blocks = (sample, f-slice)
constexpr int NT = 512;         // threads per block
constexpr int XPAD = 132;       // xs row stride: 528B = 33*16 (float4-aligned), +4 bank skew
constexpr float BN_EPS = 1e-5f;
constexpr float L2E = 1.44269504088896f;
constexpr float LN2 = 0.69314718055995f;

// Cheap manual grid barrier (R6's all-thread acquire-spin cost ~130us: 262K
// pollers saturated the LLC). Here: ONE poller per block (tid 0), RELAXED
// polls + s_sleep(32) => ~512 pollers at low rate. Arrival: fetch_add RELEASE
// (RMWs extend the release sequence, so the final value 512 synchronizes-with
// ALL arrivals). After syncthreads every thread does ONE ACQUIRE load to pull
// in remote data (mechanism correctness proven by R6's passing run).
// Counter is zeroed by an 8-byte hipMemsetAsync at launch (stream-ordered).
__device__ __forceinline__ void grid_barrier(unsigned* ctr, int tid)
{
    __threadfence();            // my prior stores visible device-wide
    __syncthreads();            // whole block done + fenced
    if (tid == 0) {
        __hip_atomic_fetch_add(ctr, 1u, __ATOMIC_RELEASE, __HIP_MEMORY_SCOPE_AGENT);
        while (__hip_atomic_load(ctr, __ATOMIC_RELAXED, __HIP_MEMORY_SCOPE_AGENT) < (unsigned)NB)
            __builtin_amdgcn_s_sleep(32);
    }
    __syncthreads();
    unsigned v = __hip_atomic_load(ctr, __ATOMIC_ACQUIRE, __HIP_MEMORY_SCOPE_AGENT);
    asm volatile("" :: "v"(v)); // keep the acquire load live
}

// Stage this block's 16-feature weight slice into LDS (R3/R6-proven path):
// wlds[k][fr] = {Wf[f][k], Wf[f][k+128], Ws[f][k], Ws[f][k+128]}.
// Reads: 16-row gather, L1/L2-hot (132KB slab shared by 64 blocks).
// Writes: contiguous ds_write_b128, 2-way bank alias (free).
__device__ __forceinline__ void stage_w(
    float4 (*wlds)[FS], const float* __restrict__ Wf, const float* __restrict__ Ws,
    int fq, int tid)
{
    for (int i = tid; i < FD * FS; i += NT) {
        int k = i >> 4, fr = i & (FS - 1);
        int row = (fq * FS + fr) * ZD;
        wlds[k][fr] = make_float4(Wf[row + k], Wf[row + FD + k],
                                  Ws[row + k], Ws[row + FD + k]);
    }
}

// Fused CGConv layer for block (s, fq): GEMM (P exp-domain -> VGPRs, Q -> 8KB
// LDS tile; x float4 from LDS, W b128 from LDS wlds = 6 ds_read_b128 per
// 4k-chunk), then in-block edge aggregation + BN partial stores (no atomics).
// agg store optional (layer 2 keeps its output in registers via aOut0/aOut1).
__device__ __forceinline__ void layer_body(
    const float (*xs)[XPAD], const float2* cs, float2 (*q)[FS],
    const float4 (*wlds)[FS],
    const float* __restrict__ Wf, const float* __restrict__ Ws,
    const float* __restrict__ bf, const float* __restrict__ bs,
    int tid, int s, int fq,
    float* __restrict__ agg, float* __restrict__ pS, float* __restrict__ pSS,
    float& aOut0, float& aOut1)
{
    const int fl = tid & (FS - 1);
    const int ig = tid >> 4;            // 0..31 -> nodes {ig, ig+32}
    const int f  = fq * FS + fl;
    const int base = s * NA;

    float aPf0=0.f,aQf0=0.f,aPs0=0.f,aQs0=0.f;
    float aPf1=0.f,aQf1=0.f,aPs1=0.f,aQs1=0.f;
    #pragma unroll 2
    for (int k = 0; k < FD; k += 4) {
        float4 x0 = *(const float4*)&xs[ig][k];       // bcast across 16 fl: free
        float4 x1 = *(const float4*)&xs[ig + 32][k];
        float4 w0 = wlds[k + 0][fl];                  // 256B/wave, 2-way alias
        float4 w1 = wlds[k + 1][fl];
        float4 w2 = wlds[k + 2][fl];
        float4 w3 = wlds[k + 3][fl];
        aPf0 = fmaf(x0.x, w0.x, aPf0); aQf0 = fmaf(x0.x, w0.y, aQf0);
        aPs0 = fmaf(x0.x, w0.z, aPs0); aQs0 = fmaf(x0.x, w0.w, aQs0);
        aPf1 = fmaf(x1.x, w0.x, aPf1); aQf1 = fmaf(x1.x, w0.y, aQf1);
        aPs1 = fmaf(x1.x, w0.z, aPs1); aQs1 = fmaf(x1.x, w0.w, aQs1);

        aPf0 = fmaf(x0.y, w1.x, aPf0); aQf0 = fmaf(x0.y, w1.y, aQf0);
        aPs0 = fmaf(x0.y, w1.z, aPs0); aQs0 = fmaf(x0.y, w1.w, aQs0);
        aPf1 = fmaf(x1.y, w1.x, aPf1); aQf1 = fmaf(x1.y, w1.y, aQf1);
        aPs1 = fmaf(x1.y, w1.z, aPs1); aQs1 = fmaf(x1.y, w1.w, aQs1);

        aPf0 = fmaf(x0.z, w2.x, aPf0); aQf0 = fmaf(x0.z, w2.y, aQf0);
        aPs0 = fmaf(x0.z, w2.z, aPs0); aQs0 = fmaf(x0.z, w2.w, aQs0);
        aPf1 = fmaf(x1.z, w2.x, aPf1); aQf1 = fmaf(x1.z, w2.y, aQf1);
        aPs1 = fmaf(x1.z, w2.z, aPs1); aQs1 = fmaf(x1.z, w2.w, aQs1);

        aPf0 = fmaf(x0.w, w3.x, aPf0); aQf0 = fmaf(x0.w, w3.y, aQf0);
        aPs0 = fmaf(x0.w, w3.z, aPs0); aQs0 = fmaf(x0.w, w3.w, aQs0);
        aPf1 = fmaf(x1.w, w3.x, aPf1); aQf1 = fmaf(x1.w, w3.y, aQf1);
        aPs1 = fmaf(x1.w, w3.z, aPs1); aQs1 = fmaf(x1.w, w3.w, aQs1);
    }
    float we0 = Wf[f*ZD + 2*FD], we1 = Wf[f*ZD + 2*FD + 1];
    float ws0 = Ws[f*ZD + 2*FD], ws1 = Ws[f*ZD + 2*FD + 1];
    float bfv = bf[f], bsv = bs[f];
    float2 c0 = cs[ig], c1 = cs[ig + 32];
    float cf0 = c0.x*we0 + c0.y*we1, cg0 = c0.x*ws0 + c0.y*ws1;
    float cf1 = c1.x*we0 + c1.y*we1, cg1 = c1.x*ws0 + c1.y*ws1;
    float Pf0 = aPf0 + cf0 + bfv, Ps0 = aPs0 + cg0 + bsv;
    float Pf1 = aPf1 + cf1 + bfv, Ps1 = aPs1 + cg1 + bsv;
    float Qf0 = aQf0 - cf0,       Qs0 = aQs0 - cg0;
    float Qf1 = aQf1 - cf1,       Qs1 = aQs1 - cg1;
    // exp-domain: sigma = rcp(1 + e^{-P}e^{-Q}), softplus*log2e = log2(1 + e^{Ps}e^{Qs})
    float2 p0 = make_float2(__builtin_amdgcn_exp2f(-Pf0*L2E), __builtin_amdgcn_exp2f(Ps0*L2E));
    float2 p1 = make_float2(__builtin_amdgcn_exp2f(-Pf1*L2E), __builtin_amdgcn_exp2f(Ps1*L2E));
    q[ig][fl]    = make_float2(__builtin_amdgcn_exp2f(-Qf0*L2E), __builtin_amdgcn_exp2f(Qs0*L2E));
    q[ig+32][fl] = make_float2(__builtin_amdgcn_exp2f(-Qf1*L2E), __builtin_amdgcn_exp2f(Qs1*L2E));
    __syncthreads();

    // ---- edge aggregation: i in {ig, ig+32}, all 64 j, dual chains ----
    float a0=0.f, a1=0.f, b0=0.f, b1=0.f;
    #pragma unroll 4
    for (int j = 0; j < NA; j += 2) {
        float2 qa = q[j][fl];            // same-address bcast per lane-group: free
        float2 qb = q[j+1][fl];
        a0 = fmaf(__builtin_amdgcn_rcpf(1.0f + p0.x*qa.x),
                  __builtin_amdgcn_logf(1.0f + p0.y*qa.y), a0);
        b0 = fmaf(__builtin_amdgcn_rcpf(1.0f + p1.x*qa.x),
                  __builtin_amdgcn_logf(1.0f + p1.y*qa.y), b0);
        a1 = fmaf(__builtin_amdgcn_rcpf(1.0f + p0.x*qb.x),
                  __builtin_amdgcn_logf(1.0f + p0.y*qb.y), a1);
        b1 = fmaf(__builtin_amdgcn_rcpf(1.0f + p1.x*qb.x),
                  __builtin_amdgcn_logf(1.0f + p1.y*qb.y), b1);
    }
    float aA = a0 + a1, aB = b0 + b1;
    {   // remove self-loop terms (j == i)
        float2 qv0 = q[ig][fl];
        aA -= __builtin_amdgcn_rcpf(1.0f + p0.x*qv0.x) *
              __builtin_amdgcn_logf(1.0f + p0.y*qv0.y);
        float2 qv1 = q[ig+32][fl];
        aB -= __builtin_amdgcn_rcpf(1.0f + p1.x*qv1.x) *
              __builtin_amdgcn_logf(1.0f + p1.y*qv1.y);
    }
    aA *= LN2; aB *= LN2;               // log2 -> ln once, outside the sum
    if (agg) {
        agg[(base + ig) * FD + f]      = aA;
        agg[(base + ig + 32) * FD + f] = aB;
    }

    // ---- BN partial stats: reduce 64 i per f in-block, plain stores ----
    __syncthreads();                    // all q reads done; alias as scratch
    float* sm = (float*)q;              // 2048 floats available, need 1024
    sm[tid]      = aA + aB;
    sm[NT + tid] = aA*aA + aB*aB;
    __syncthreads();
    if (tid < FS) {
        float sv = 0.f, qv = 0.f;
        #pragma unroll
        for (int r = 0; r < 32; ++r) {
            sv += sm[r * FS + tid];
            qv += sm[NT + r * FS + tid];
        }
        pS [s * FD + fq * FS + tid] = sv;   // distinct slot per block: no atomics
        pSS[s * FD + fq * FS + tid] = qv;
    }
    aOut0 = aA; aOut1 = aB;
}

// ONE persistent kernel (structure + numerics proven by R6): L1(gemm+edge) ->
// grid barrier -> x1-in-LDS + L2(gemm+edge, output in VGPRs) -> grid barrier
// -> epilogue. P/Q, x1, agg2 never touch HBM; 1 launch instead of 3.
// Co-residency by construction: 74.5KB LDS -> 2 blocks/CU x 256 CU = 512.
__global__ __launch_bounds__(NT, 4) void fused_kernel(
    const float* __restrict__ X0, const float* __restrict__ C,
    const float* __restrict__ Wf1, const float* __restrict__ bf1,
    const float* __restrict__ Ws1, const float* __restrict__ bs1,
    const float* __restrict__ g1, const float* __restrict__ be1,
    const float* __restrict__ Wf2, const float* __restrict__ bf2,
    const float* __restrict__ Ws2, const float* __restrict__ bs2,
    const float* __restrict__ g2, const float* __restrict__ be2,
    float* __restrict__ agg1,
    float* __restrict__ pS1, float* __restrict__ pSS1,
    float* __restrict__ pS2, float* __restrict__ pSS2,
    unsigned* __restrict__ bars,
    float* __restrict__ out)
{
    __shared__ __align__(16) float xs[NA][XPAD];  // 33 KB: x0, then x1 in place
    __shared__ float4 wlds[FD][FS];               // 32 KB: W1, then W2 slice
    __shared__ float2 q[NA][FS];                  //  8 KB (aliased as scratch)
    __shared__ float2 cs[NA];                     // 0.5 KB
    __shared__ float bnsc[FD], bnsh[FD];          //  1 KB   (total 74.5 KB -> 2/CU)

    const int tid = threadIdx.x, bid = blockIdx.x;
    const int s = bid & (NS - 1), fq = bid >> 6;  // sample f-slices -> same XCD
    const int fl = tid & (FS - 1), ig = tid >> 4;
    const int f  = fq * FS + fl;
    const int base = s * NA;

    // ---- phase 1: stage + layer 1 ----
    stage_w(wlds, Wf1, Ws1, fq, tid);
    const float4* Xv = (const float4*)(X0 + base * FD);
    for (int idx = tid; idx < NA * FD / 4; idx += NT) {
        int n = idx >> 5, k4 = idx & 31;
        *(float4*)&xs[n][k4 * 4] = Xv[idx];
    }
    if (tid < NA) cs[tid] = ((const float2*)C)[base + tid];
    __syncthreads();
    float d0, d1;
    layer_body(xs, cs, q, wlds, Wf1, Ws1, bf1, bs1, tid, s, fq,
               agg1, pS1, pSS1, d0, d1);

    grid_barrier(&bars[0], tid);        // agg1 + stats1 partials visible

    // ---- phase 2: W2 restage + stats1 reduce + x1 in place + layer 2 ----
    stage_w(wlds, Wf2, Ws2, fq, tid);
    {   // stats1 partial reduce, all 512 threads (4 sample-groups x 128 f)
        int fr = tid & (FD - 1), sq = tid >> 7;
        float sv = 0.f, qv = 0.f;
        #pragma unroll
        for (int s2 = 0; s2 < NS / 4; ++s2) {
            int si = sq * (NS / 4) + s2;
            sv += pS1[si * FD + fr];
            qv += pSS1[si * FD + fr];
        }
        float* sm = (float*)q;
        sm[tid] = sv;
        sm[NT + tid] = qv;
    }
    __syncthreads();
    if (tid < FD) {
        const float* sm = (const float*)q;
        float sv = sm[tid] + sm[FD + tid] + sm[2*FD + tid] + sm[3*FD + tid];
        float qv = sm[NT + tid] + sm[NT + FD + tid] + sm[NT + 2*FD + tid] + sm[NT + 3*FD + tid];
        float m  = sv * (1.0f / NN);
        float v  = qv * (1.0f / NN) - m * m;
        float sc = g1[tid] * rsqrtf(v + BN_EPS);
        bnsc[tid] = sc;
        bnsh[tid] = be1[tid] - m * sc;
    }
    __syncthreads();
    const float4* Av = (const float4*)(agg1 + base * FD);
    for (int idx = tid; idx < NA * FD / 4; idx += NT) {
        int n = idx >> 5, k4 = (idx & 31) * 4;
        float4 x = *(const float4*)&xs[n][k4];    // x0 still in LDS
        float4 a = Av[idx];
        float4 r;
        r.x = fmaxf(fmaf(a.x, bnsc[k4 + 0], bnsh[k4 + 0]) + x.x, 0.0f);
        r.y = fmaxf(fmaf(a.y, bnsc[k4 + 1], bnsh[k4 + 1]) + x.y, 0.0f);
        r.z = fmaxf(fmaf(a.z, bnsc[k4 + 2], bnsh[k4 + 2]) + x.z, 0.0f);
        r.w = fmaxf(fmaf(a.w, bnsc[k4 + 3], bnsh[k4 + 3]) + x.w, 0.0f);
        *(float4*)&xs[n][k4] = r;                 // xs := x1 (never hits HBM)
    }
    __syncthreads();
    float aA2, aB2;                               // layer-2 output: registers only
    layer_body(xs, cs, q, wlds, Wf2, Ws2, bf2, bs2, tid, s, fq,
               (float*)nullptr, pS2, pSS2, aA2, aB2);

    grid_barrier(&bars[1], tid);        // stats2 partials visible

    // ---- epilogue: stats2 reduce (own 16 f's) + out from registers/LDS ----
    {
        int fr = tid & (FS - 1), sq2 = tid >> 4;  // 32 groups x 2 samples
        float sv = 0.f, qv = 0.f;
        #pragma unroll
        for (int t = 0; t < 2; ++t) {
            int si = sq2 * 2 + t;
            sv += pS2[si * FD + fq * FS + fr];
            qv += pSS2[si * FD + fq * FS + fr];
        }
        float* sm = (float*)q;                    // q dead; barrier sync'd
        sm[tid] = sv;
        sm[NT + tid] = qv;
    }
    __syncthreads();
    if (tid < FS) {
        const float* sm = (const float*)q;
        float sv = 0.f, qv = 0.f;
        #pragma unroll
        for (int g = 0; g < 32; ++g) {
            sv += sm[g * FS + tid];
            qv += sm[NT + g * FS + tid];
        }
        float m  = sv * (1.0f / NN);
        float v  = qv * (1.0f / NN) - m * m;
        float sc = g2[fq * FS + tid] * rsqrtf(v + BN_EPS);
        bnsc[tid] = sc;
        bnsh[tid] = be2[fq * FS + tid] - m * sc;
    }
    __syncthreads();
    {
        float sc = bnsc[fl], sh = bnsh[fl];
        out[(base + ig) * FD + f]      = fmaxf(fmaf(aA2, sc, sh) + xs[ig][f], 0.0f);
        out[(base + ig + 32) * FD + f] = fmaxf(fmaf(aB2, sc, sh) + xs[ig + 32][f], 0.0f);
    }
}

extern "C" void kernel_launch(void* const* d_in, const int* in_sizes, int n_in,
                              void* d_out, int out_size, void* d_ws, size_t ws_size,
                              hipStream_t stream) {
    const float* gnn_in  = (const float*)d_in[0];
    const float* centers = (const float*)d_in[1];
    // d_in[2]=src, d_in[3]=dst: structure known (fully connected per sample) — unused
    const float* Wf1 = (const float*)d_in[4];
    const float* bf1 = (const float*)d_in[5];
    const float* Ws1 = (const float*)d_in[6];
    const float* bs1 = (const float*)d_in[7];
    const float* g1  = (const float*)d_in[8];
    const float* be1 = (const float*)d_in[9];
    const float* Wf2 = (const float*)d_in[10];
    const float* bf2 = (const float*)d_in[11];
    const float* Ws2 = (const float*)d_in[12];
    const float* bs2 = (const float*)d_in[13];
    const float* g2  = (const float*)d_in[14];
    const float* be2 = (const float*)d_in[15];

    char* ws = (char*)d_ws;
    float*    agg1 = (float*)(ws);                              // 2 MB
    float*    pS1  = (float*)(ws + (2 << 20));                  // 32 KB
    float*    pSS1 = (float*)(ws + (2 << 20) + (32 << 10));     // 32 KB
    float*    pS2  = (float*)(ws + (2 << 20) + (64 << 10));     // 32 KB
    float*    pSS2 = (float*)(ws + (2 << 20) + (96 << 10));     // 32 KB
    unsigned* bars = (unsigned*)(ws + (2 << 20) + (128 << 10)); // 8 B

    hipMemsetAsync(bars, 0, 2 * sizeof(unsigned), stream);      // arm barriers

    fused_kernel<<<NB, NT, 0, stream>>>(
        gnn_in, centers,
        Wf1, bf1, Ws1, bs1, g1, be1,
        Wf2, bf2, Ws2, bs2, g2, be2,
        agg1, pS1, pSS1, pS2, pSS2, bars, (float*)d_out);
}

// Round 9
// 138.307 us; speedup vs baseline: 2.4679x; 2.4679x over previous
//
#include <hip/hip_runtime.h>

constexpr int NS = 64;          // samples
constexpr int NA = 64;          // agents per sample
constexpr int NN = NS * NA;     // 4096 nodes
constexpr int FD = 128;         // feature dim
constexpr int ZD = 2 * FD + 2;  // 258
constexpr int FS = 16;          // feature-slice width per block
constexpr int NB = NS * (FD / FS); // 512 blocks = (sample, f-slice)
constexpr int NT = 512;         // threads per block
constexpr int XPAD = 132;       // xs row stride: 528B = 33*16 (float4-aligned), +4 bank skew
constexpr float BN_EPS = 1e-5f;
constexpr float L2E = 1.44269504088896f;
constexpr float LN2 = 0.69314718055995f;

// Stage this block's 16-feature weight slice into LDS (R3/R6-proven):
// wlds[k][fr] = {Wf[f][k], Wf[f][k+128], Ws[f][k], Ws[f][k+128]}.
__device__ __forceinline__ void stage_w(
    float4 (*wlds)[FS], const float* __restrict__ Wf, const float* __restrict__ Ws,
    int fq, int tid)
{
    for (int i = tid; i < FD * FS; i += NT) {
        int k = i >> 4, fr = i & (FS - 1);
        int row = (fq * FS + fr) * ZD;
        wlds[k][fr] = make_float4(Wf[row + k], Wf[row + FD + k],
                                  Ws[row + k], Ws[row + FD + k]);
    }
}

// Post-GEMM tail shared by both layer forms: bias/centers fold, exp-domain
// transform, Q -> LDS tile, edge aggregation, BN partial stores.
__device__ __forceinline__ void layer_tail(
    float aPf0, float aQf0, float aPs0, float aQs0,
    float aPf1, float aQf1, float aPs1, float aQs1,
    const float2* cs, float2 (*q)[FS],
    const float* __restrict__ Wf, const float* __restrict__ Ws,
    const float* __restrict__ bf, const float* __restrict__ bs,
    int tid, int fl, int ig, int f, int s, int fq, int base,
    float* __restrict__ agg, float* __restrict__ pS, float* __restrict__ pSS,
    float& aOut0, float& aOut1)
{
    float we0 = Wf[f*ZD + 2*FD], we1 = Wf[f*ZD + 2*FD + 1];
    float ws0 = Ws[f*ZD + 2*FD], ws1 = Ws[f*ZD + 2*FD + 1];
    float bfv = bf[f], bsv = bs[f];
    float2 c0 = cs[ig], c1 = cs[ig + 32];
    float cf0 = c0.x*we0 + c0.y*we1, cg0 = c0.x*ws0 + c0.y*ws1;
    float cf1 = c1.x*we0 + c1.y*we1, cg1 = c1.x*ws0 + c1.y*ws1;
    float Pf0 = aPf0 + cf0 + bfv, Ps0 = aPs0 + cg0 + bsv;
    float Pf1 = aPf1 + cf1 + bfv, Ps1 = aPs1 + cg1 + bsv;
    float Qf0 = aQf0 - cf0,       Qs0 = aQs0 - cg0;
    float Qf1 = aQf1 - cf1,       Qs1 = aQs1 - cg1;
    // exp-domain: sigma = rcp(1 + e^{-P}e^{-Q}), softplus*log2e = log2(1 + e^{Ps}e^{Qs})
    float2 p0 = make_float2(__builtin_amdgcn_exp2f(-Pf0*L2E), __builtin_amdgcn_exp2f(Ps0*L2E));
    float2 p1 = make_float2(__builtin_amdgcn_exp2f(-Pf1*L2E), __builtin_amdgcn_exp2f(Ps1*L2E));
    q[ig][fl]    = make_float2(__builtin_amdgcn_exp2f(-Qf0*L2E), __builtin_amdgcn_exp2f(Qs0*L2E));
    q[ig+32][fl] = make_float2(__builtin_amdgcn_exp2f(-Qf1*L2E), __builtin_amdgcn_exp2f(Qs1*L2E));
    __syncthreads();

    // ---- edge aggregation: i in {ig, ig+32}, all 64 j, dual chains ----
    float a0=0.f, a1=0.f, b0=0.f, b1=0.f;
    #pragma unroll 4
    for (int j = 0; j < NA; j += 2) {
        float2 qa = q[j][fl];            // same-address bcast per lane-group: free
        float2 qb = q[j+1][fl];
        a0 = fmaf(__builtin_amdgcn_rcpf(1.0f + p0.x*qa.x),
                  __builtin_amdgcn_logf(1.0f + p0.y*qa.y), a0);
        b0 = fmaf(__builtin_amdgcn_rcpf(1.0f + p1.x*qa.x),
                  __builtin_amdgcn_logf(1.0f + p1.y*qa.y), b0);
        a1 = fmaf(__builtin_amdgcn_rcpf(1.0f + p0.x*qb.x),
                  __builtin_amdgcn_logf(1.0f + p0.y*qb.y), a1);
        b1 = fmaf(__builtin_amdgcn_rcpf(1.0f + p1.x*qb.x),
                  __builtin_amdgcn_logf(1.0f + p1.y*qb.y), b1);
    }
    float aA = a0 + a1, aB = b0 + b1;
    {   // remove self-loop terms (j == i)
        float2 qv0 = q[ig][fl];
        aA -= __builtin_amdgcn_rcpf(1.0f + p0.x*qv0.x) *
              __builtin_amdgcn_logf(1.0f + p0.y*qv0.y);
        float2 qv1 = q[ig+32][fl];
        aB -= __builtin_amdgcn_rcpf(1.0f + p1.x*qv1.x) *
              __builtin_amdgcn_logf(1.0f + p1.y*qv1.y);
    }
    aA *= LN2; aB *= LN2;               // log2 -> ln once, outside the sum
    agg[(base + ig) * FD + f]      = aA;
    agg[(base + ig + 32) * FD + f] = aB;

    // ---- BN partial stats: reduce 64 i per f in-block, plain stores ----
    __syncthreads();                    // all q reads done; alias as scratch
    float* sm = (float*)q;              // 2048 floats available, need 1024
    sm[tid]      = aA + aB;
    sm[NT + tid] = aA*aA + aB*aB;
    __syncthreads();
    if (tid < FS) {
        float sv = 0.f, qv = 0.f;
        #pragma unroll
        for (int r = 0; r < 32; ++r) {
            sv += sm[r * FS + tid];
            qv += sm[NT + r * FS + tid];
        }
        pS [s * FD + fq * FS + tid] = sv;   // distinct slot per block: no atomics
        pSS[s * FD + fq * FS + tid] = qv;
    }
    aOut0 = aA; aOut1 = aB;
}

// 8-FMA x 4k GEMM step (identical FMA order in both layer forms).
#define GEMM_STEP(xv, wv) \
    aPf0 = fmaf(x0.xv, wv.x, aPf0); aQf0 = fmaf(x0.xv, wv.y, aQf0); \
    aPs0 = fmaf(x0.xv, wv.z, aPs0); aQs0 = fmaf(x0.xv, wv.w, aQs0); \
    aPf1 = fmaf(x1.xv, wv.x, aPf1); aQf1 = fmaf(x1.xv, wv.y, aQf1); \
    aPs1 = fmaf(x1.xv, wv.z, aPs1); aQs1 = fmaf(x1.xv, wv.w, aQs1);

// Layer 1: W via LDS wlds (R6-proven GEMM body). Blocks with s==0 also pack
// PK2[k][f] for layer 2 (one fq-slice each, distinct addresses -> no race,
// ~3us on 8 of 512 blocks, hidden under the rest).
__global__ __launch_bounds__(NT) void layer1_kernel(
    const float* __restrict__ X0, const float* __restrict__ C,
    const float* __restrict__ Wf, const float* __restrict__ Ws,
    const float* __restrict__ bf, const float* __restrict__ bs,
    const float* __restrict__ Wf2, const float* __restrict__ Ws2,
    float4* __restrict__ PK2,
    float* __restrict__ agg, float* __restrict__ pS, float* __restrict__ pSS)
{
    __shared__ __align__(16) float xs[NA][XPAD];  // 33 KB
    __shared__ float4 wlds[FD][FS];               // 32 KB
    __shared__ float2 q[NA][FS];                  //  8 KB
    __shared__ float2 cs[NA];                     // 0.5 KB (73.5 KB -> 2 blocks/CU)
    int tid = threadIdx.x, bid = blockIdx.x;
    int s = bid & (NS - 1), fq = bid >> 6;  // 8 f-slices of a sample -> same XCD
    int base = s * NA;
    if (s == 0) {   // pack W2 slice fq for layer 2 (16 consecutive float4/row: coalesced)
        for (int i = tid; i < FD * FS; i += NT) {
            int k = i >> 4, fr = i & (FS - 1);
            int f2 = fq * FS + fr;
            PK2[k * FD + f2] = make_float4(Wf2[f2*ZD+k], Wf2[f2*ZD+FD+k],
                                           Ws2[f2*ZD+k], Ws2[f2*ZD+FD+k]);
        }
    }
    stage_w(wlds, Wf, Ws, fq, tid);
    const float4* Xv = (const float4*)(X0 + base * FD);
    for (int idx = tid; idx < NA * FD / 4; idx += NT) {
        int n = idx >> 5, k4 = idx & 31;
        *(float4*)&xs[n][k4 * 4] = Xv[idx];
    }
    if (tid < NA) cs[tid] = ((const float2*)C)[base + tid];
    __syncthreads();

    const int fl = tid & (FS - 1), ig = tid >> 4;
    const int f  = fq * FS + fl;
    float aPf0=0.f,aQf0=0.f,aPs0=0.f,aQs0=0.f;
    float aPf1=0.f,aQf1=0.f,aPs1=0.f,aQs1=0.f;
    #pragma unroll 2
    for (int k = 0; k < FD; k += 4) {
        float4 x0 = *(const float4*)&xs[ig][k];
        float4 x1 = *(const float4*)&xs[ig + 32][k];
        float4 w0 = wlds[k + 0][fl];
        float4 w1 = wlds[k + 1][fl];
        float4 w2 = wlds[k + 2][fl];
        float4 w3 = wlds[k + 3][fl];
        GEMM_STEP(x, w0) GEMM_STEP(y, w1) GEMM_STEP(z, w2) GEMM_STEP(w, w3)
    }
    float d0, d1;
    layer_tail(aPf0,aQf0,aPs0,aQs0, aPf1,aQf1,aPs1,aQs1,
               cs, q, Wf, Ws, bf, bs, tid, fl, ig, f, s, fq, base,
               agg, pS, pSS, d0, d1);
}

// Layer 2: W streams from packed PK2 via VMEM (256B/wave contiguous,
// consecutive blocks share the slice -> XCD-L2 hot). No wlds: LDS 42.5 KB,
// LDS pipe carries only x reads (~4us/CU vs ~13). Stats1 reduce + x1 staging
// (LDS + global for the epilogue), then GEMM+edge.
__global__ __launch_bounds__(NT) void layer2_kernel(
    const float* __restrict__ X0, const float* __restrict__ agg1,
    const float* __restrict__ C,
    const float* __restrict__ pS1, const float* __restrict__ pSS1,
    const float* __restrict__ g1, const float* __restrict__ be1,
    const float* __restrict__ Wf, const float* __restrict__ Ws,
    const float* __restrict__ bf, const float* __restrict__ bs,
    const float4* __restrict__ PK2,
    float* __restrict__ x1, float* __restrict__ agg2,
    float* __restrict__ pS2, float* __restrict__ pSS2)
{
    __shared__ __align__(16) float xs[NA][XPAD];  // 33 KB
    __shared__ float2 q[NA][FS];                  //  8 KB
    __shared__ float2 cs[NA];
    __shared__ float bnsc[FD], bnsh[FD];          // (42.5 KB total)
    int tid = threadIdx.x, bid = blockIdx.x;
    int s = bid & (NS - 1), fq = bid >> 6;
    int base = s * NA;
    {   // stats1 partial reduce, all 512 threads (4 sample-groups x 128 f)
        int fr = tid & (FD - 1), sq = tid >> 7;
        float sv = 0.f, qv = 0.f;
        #pragma unroll
        for (int s2 = 0; s2 < NS / 4; ++s2) {
            int si = sq * (NS / 4) + s2;
            sv += pS1[si * FD + fr];
            qv += pSS1[si * FD + fr];
        }
        float* sm = (float*)q;          // scratch (q dead until tail)
        sm[tid] = sv;
        sm[NT + tid] = qv;
    }
    if (tid < NA) cs[tid] = ((const float2*)C)[base + tid];
    __syncthreads();
    if (tid < FD) {
        const float* sm = (const float*)q;
        float sv = sm[tid] + sm[FD + tid] + sm[2*FD + tid] + sm[3*FD + tid];
        float qv = sm[NT + tid] + sm[NT + FD + tid] + sm[NT + 2*FD + tid] + sm[NT + 3*FD + tid];
        float m  = sv * (1.0f / NN);
        float v  = qv * (1.0f / NN) - m * m;
        float sc = g1[tid] * rsqrtf(v + BN_EPS);
        bnsc[tid] = sc;
        bnsh[tid] = be1[tid] - m * sc;
    }
    __syncthreads();
    const float4* Xv  = (const float4*)(X0 + base * FD);
    const float4* Av  = (const float4*)(agg1 + base * FD);
    float4*       X1v = (float4*)(x1 + base * FD);
    for (int idx = tid; idx < NA * FD / 4; idx += NT) {
        int n = idx >> 5, k4 = (idx & 31) * 4;
        float4 x = Xv[idx], a = Av[idx];
        float4 r;
        r.x = fmaxf(fmaf(a.x, bnsc[k4 + 0], bnsh[k4 + 0]) + x.x, 0.0f);
        r.y = fmaxf(fmaf(a.y, bnsc[k4 + 1], bnsh[k4 + 1]) + x.y, 0.0f);
        r.z = fmaxf(fmaf(a.z, bnsc[k4 + 2], bnsh[k4 + 2]) + x.z, 0.0f);
        r.w = fmaxf(fmaf(a.w, bnsc[k4 + 3], bnsh[k4 + 3]) + x.w, 0.0f);
        *(float4*)&xs[n][k4] = r;
        X1v[idx] = r;                   // x1 for the epilogue kernel
    }
    __syncthreads();

    const int fl = tid & (FS - 1), ig = tid >> 4;
    const int f  = fq * FS + fl;
    const float4* Wp = PK2 + f;         // PK2[k][f]: wave reads 256B contiguous
    float aPf0=0.f,aQf0=0.f,aPs0=0.f,aQs0=0.f;
    float aPf1=0.f,aQf1=0.f,aPs1=0.f,aQs1=0.f;
    #pragma unroll 2
    for (int k = 0; k < FD; k += 4) {
        float4 x0 = *(const float4*)&xs[ig][k];
        float4 x1v = *(const float4*)&xs[ig + 32][k];
        float4 w0 = Wp[(k + 0) * FD];
        float4 w1 = Wp[(k + 1) * FD];
        float4 w2 = Wp[(k + 2) * FD];
        float4 w3 = Wp[(k + 3) * FD];
        float4 x1 = x1v;
        GEMM_STEP(x, w0) GEMM_STEP(y, w1) GEMM_STEP(z, w2) GEMM_STEP(w, w3)
    }
    float d0, d1;
    layer_tail(aPf0,aQf0,aPs0,aQs0, aPf1,aQf1,aPs1,aQs1,
               cs, q, Wf, Ws, bf, bs, tid, fl, ig, f, s, fq, base,
               agg2, pS2, pSS2, d0, d1);
}

// Epilogue: parallel stats2 reduce per block, out = relu(BN2(agg2) + x1).
__global__ __launch_bounds__(256) void out_kernel(
    const float4* __restrict__ x1, const float4* __restrict__ agg2,
    const float* __restrict__ pS2, const float* __restrict__ pSS2,
    const float* __restrict__ g2, const float* __restrict__ be2,
    float4* __restrict__ out)
{
    __shared__ float sm[1024];
    __shared__ float sc[FD], sh[FD];
    int tid = threadIdx.x;
    {   // 256 threads = 128 f x 2 sample-halves
        int fr = tid & (FD - 1), sq = tid >> 7;
        float sv = 0.f, qv = 0.f;
        #pragma unroll
        for (int s2 = 0; s2 < NS / 2; ++s2) {
            int si = sq * (NS / 2) + s2;
            sv += pS2[si * FD + fr];
            qv += pSS2[si * FD + fr];
        }
        sm[tid] = sv;
        sm[512 + tid] = qv;
    }
    __syncthreads();
    if (tid < FD) {
        float sv = sm[tid] + sm[FD + tid];
        float qv = sm[512 + tid] + sm[512 + FD + tid];
        float m  = sv * (1.0f / NN);
        float v  = qv * (1.0f / NN) - m * m;
        float scl = g2[tid] * rsqrtf(v + BN_EPS);
        sc[tid] = scl;
        sh[tid] = be2[tid] - m * scl;
    }
    __syncthreads();
    int idx = blockIdx.x * 256 + tid;   // < NN*FD/4
    int f0 = (idx & 31) * 4;
    float4 xv = x1[idx], av = agg2[idx];
    float4 r;
    r.x = fmaxf(fmaf(av.x, sc[f0 + 0], sh[f0 + 0]) + xv.x, 0.0f);
    r.y = fmaxf(fmaf(av.y, sc[f0 + 1], sh[f0 + 1]) + xv.y, 0.0f);
    r.z = fmaxf(fmaf(av.z, sc[f0 + 2], sh[f0 + 2]) + xv.z, 0.0f);
    r.w = fmaxf(fmaf(av.w, sc[f0 + 3], sh[f0 + 3]) + xv.w, 0.0f);
    out[idx] = r;
}

extern "C" void kernel_launch(void* const* d_in, const int* in_sizes, int n_in,
                              void* d_out, int out_size, void* d_ws, size_t ws_size,
                              hipStream_t stream) {
    const float* gnn_in  = (const float*)d_in[0];
    const float* centers = (const float*)d_in[1];
    // d_in[2]=src, d_in[3]=dst: structure known (fully connected per sample) — unused
    const float* Wf1 = (const float*)d_in[4];
    const float* bf1 = (const float*)d_in[5];
    const float* Ws1 = (const float*)d_in[6];
    const float* bs1 = (const float*)d_in[7];
    const float* g1  = (const float*)d_in[8];
    const float* be1 = (const float*)d_in[9];
    const float* Wf2 = (const float*)d_in[10];
    const float* bf2 = (const float*)d_in[11];
    const float* Ws2 = (const float*)d_in[12];
    const float* bs2 = (const float*)d_in[13];
    const float* g2  = (const float*)d_in[14];
    const float* be2 = (const float*)d_in[15];

    char* ws = (char*)d_ws;
    float*  agg1 = (float*)(ws);                             // 2 MB
    float*  agg2 = (float*)(ws + (2 << 20));                 // 2 MB
    float*  x1   = (float*)(ws + (4 << 20));                 // 2 MB
    float*  p1S  = (float*)(ws + (6 << 20));                 // 32 KB
    float*  p1SS = (float*)(ws + (6 << 20) + (32 << 10));    // 32 KB
    float*  p2S  = (float*)(ws + (6 << 20) + (64 << 10));    // 32 KB
    float*  p2SS = (float*)(ws + (6 << 20) + (96 << 10));    // 32 KB
    float4* PK2  = (float4*)(ws + (6 << 20) + (128 << 10));  // 256 KB

    layer1_kernel<<<NB, NT, 0, stream>>>(gnn_in, centers, Wf1, Ws1, bf1, bs1,
                                         Wf2, Ws2, PK2, agg1, p1S, p1SS);
    layer2_kernel<<<NB, NT, 0, stream>>>(gnn_in, agg1, centers, p1S, p1SS, g1, be1,
                                         Wf2, Ws2, bf2, bs2, PK2,
                                         x1, agg2, p2S, p2SS);
    out_kernel<<<NN * FD / 4 / 256, 256, 0, stream>>>(
        (const float4*)x1, (const float4*)agg2, p2S, p2SS, g2, be2, (float4*)d_out);
}